// Round 7
// baseline (50.846 us; speedup 1.0000x reference)
//
#include <hip/hip_runtime.h>
#include <hip/hip_bf16.h>

// int4-dequant GEMM, M=32 (last token), K=4096, N=32000 (of 32064 padded).
// qweight [K][16032] int32, ONE BYTE per word (upper 24 bits zero):
//   lo nibble = even col, hi nibble = odd col. w[k][n] = (q - z)*s, g = k/128.
//
// Round 7: BN=128 (250 blocks, single scheduling round, 256B contiguous
// qweight slice per row per block -> 2x DRAM page locality, dwordx4 loads).
//  - prep packs A (x last token, f32->f16) into d_ws fragments; shared
//    k-bijection kappa(h,j)=8h+j for A and B so HW k-order cancels.
//  - aws A-fragments double-buffered (prefetched 1 k-step ahead)
//  - scales/qzeros raw words prefetched 1 group (4 t) ahead
//  - dequant: tcomb=(w1<<16)|w0, mask-only nibble extract:
//    even cols: (tcomb & 0x000F000F)|0x64006400, vz=1024+z,   vs=s
//    odd  cols: (tcomb & 0x00F000F0)|0x64006400, vz=1024+16z, vs=s/16
//  - epilogue reduction in 2 phases (mblk 0 then mblk 1), 64 KB LDS reused.
// Lane c owns phys cols 8c+s (s=0..7); one dwordx4/row covers all 8 subs.
// No nontemporal loads (measured -4us in r5).

typedef _Float16 f16x8 __attribute__((ext_vector_type(8)));
typedef _Float16 f16x2 __attribute__((ext_vector_type(2)));
typedef float f32x4 __attribute__((ext_vector_type(4)));
typedef int i32x2 __attribute__((ext_vector_type(2)));
typedef int i32x4 __attribute__((ext_vector_type(4)));

#define K_DIM 4096
#define NP 16032       // packed words per qweight/qzeros row
#define NSC 32064      // scales row pitch
#define NOUT 32000
#define S_LEN 64
#define QROWB ((size_t)NP * 4)          // bytes per qweight row
#define QSTEP (32u * (uint32_t)NP * 4u) // byte advance per k-step (32 rows)

// ---- pre-kernel: pack x[:,63,:] (f32) into A fragments (f16) ----
// aws[((ks*2 + mblk)*64 + h*16 + (m&15))*8 + j] = A[m][32ks + 8h + j]
// Thread (m, q): reads 32 B contiguous -> coalesced; scattered 16 B writes.
__global__ void prep_a_kernel(const float* __restrict__ x,
                              _Float16* __restrict__ aws) {
    int tid = blockIdx.x * 256 + threadIdx.x;   // 0..16383
    int m = tid >> 9;           // 0..31
    int q = tid & 511;          // 8-wide k group
    const float* xp = x + ((size_t)m * S_LEN + (S_LEN - 1)) * K_DIM + q * 8;
    f32x4 u0 = *(const f32x4*)xp;
    f32x4 u1 = *(const f32x4*)(xp + 4);
    int ks = q >> 2;
    int h = q & 3;
    int mblk = m >> 4;
    f16x8 d;
#pragma unroll
    for (int j = 0; j < 4; ++j) {
        d[j] = (_Float16)u0[j];
        d[4 + j] = (_Float16)u1[j];
    }
    *(f16x8*)(aws + ((size_t)((ks * 2 + mblk) * 64 + h * 16 + (m & 15))) * 8) = d;
}

// ---- main kernel ----
__global__ __launch_bounds__(512, 2)
void q4gemm_kernel(const int* __restrict__ qw,
                   const float* __restrict__ scales,
                   const int* __restrict__ qzeros,
                   const float* __restrict__ bias,
                   const _Float16* __restrict__ aws,
                   float* __restrict__ out) {
    __shared__ float red[8 * 2048];   // 64 KB, reused across 2 epilogue phases

    const int tid = threadIdx.x;
    const int w = tid >> 6;          // wave 0..7 (K-chunk: k in [512w, 512w+512))
    const int l = tid & 63;
    const int h = l >> 4;            // k lane-group 0..3 (rows 8h+j)
    const int c = l & 15;            // lane's column group: phys cols 8c+s
    const int n0 = blockIdx.x * 128; // 128 output cols per block
    const int np0 = n0 >> 1;         // 64 packed words per block

    const char* qwb = (const char*)qw;
    uint32_t qoff = (uint32_t)((w * 512 + 8 * h) * (size_t)NP + np0 + 4 * c) * 4u;

    f32x4 acc0[8] = {};   // mblk 0, sub s = 2q+o
    f32x4 acc1[8] = {};   // mblk 1
    f16x2 vz[8], vs[8];   // expanded per-group constants
    f32x4 gsc0, gsc1;     // raw next-group scales (8 cols)
    i32x4 gzw;            // raw next-group zeros (4 words)
    i32x4 qa[8], qb[8];
    f16x8 afa0, afa1, afb0, afb1;

#define QLD(buf)                                                              \
    do {                                                                      \
        _Pragma("unroll") for (int j = 0; j < 8; ++j)                         \
            buf[j] = *(const i32x4*)(qwb + qoff + (size_t)j * QROWB);         \
        qoff += QSTEP;                                                        \
    } while (0)

#define GRP_LOAD(g)                                                           \
    do {                                                                      \
        int gg = (g) > 31 ? 31 : (g);                                         \
        gsc0 = *(const f32x4*)(scales + (size_t)gg * NSC + n0 + 8 * c);       \
        gsc1 = *(const f32x4*)(scales + (size_t)gg * NSC + n0 + 8 * c + 4);   \
        gzw = *(const i32x4*)(qzeros + (size_t)gg * NP + np0 + 4 * c);        \
    } while (0)

#define GRP_EXPAND()                                                          \
    do {                                                                      \
        _Pragma("unroll") for (int s = 0; s < 8; ++s) {                       \
            const int q = s >> 1, o = s & 1;                                  \
            int zn = (gzw[q] >> (4 * o)) & 15;                                \
            int z16 = 0x6400 | (o ? (zn << 4) : zn);                          \
            int zp = z16 | (z16 << 16);                                       \
            vz[s] = __builtin_bit_cast(f16x2, zp);                            \
            float sraw = (s < 4) ? gsc0[s] : gsc1[s - 4];                     \
            float sf = sraw * (o ? 0.0625f : 1.0f);                           \
            _Float16 hf = (_Float16)sf;                                       \
            f16x2 sp = {hf, hf};                                              \
            vs[s] = sp;                                                       \
        }                                                                     \
    } while (0)

#define ALD(A0, A1, tloc)                                                     \
    do {                                                                      \
        int ksg_ = w * 16 + (tloc);                                           \
        A0 = *(const f16x8*)(aws + ((size_t)(ksg_ * 2 + 0) * 64 + l) * 8);    \
        A1 = *(const f16x8*)(aws + ((size_t)(ksg_ * 2 + 1) * 64 + l) * 8);    \
    } while (0)

#define COMPUTE(buf, A0, A1)                                                  \
    do {                                                                      \
        _Pragma("unroll") for (int q = 0; q < 4; ++q) {                       \
            int tc[4];                                                        \
            _Pragma("unroll") for (int p = 0; p < 4; ++p)                     \
                tc[p] = (buf[2 * p + 1][q] << 16) | buf[2 * p][q];            \
            _Pragma("unroll") for (int o = 0; o < 2; ++o) {                   \
                const int s = 2 * q + o;                                      \
                const int msk = o ? 0x00F000F0 : 0x000F000F;                  \
                int4 bi;                                                      \
                _Pragma("unroll") for (int p = 0; p < 4; ++p) {               \
                    int vqi = (tc[p] & msk) | 0x64006400;                     \
                    f16x2 vq = __builtin_bit_cast(f16x2, vqi);                \
                    f16x2 r = (vq - vz[s]) * vs[s];                           \
                    bi[p] = __builtin_bit_cast(int, r);                       \
                }                                                             \
                f16x8 b = __builtin_bit_cast(f16x8, bi);                      \
                acc0[s] = __builtin_amdgcn_mfma_f32_16x16x32_f16(A0, b, acc0[s], 0, 0, 0); \
                acc1[s] = __builtin_amdgcn_mfma_f32_16x16x32_f16(A1, b, acc1[s], 0, 0, 0); \
            }                                                                 \
        }                                                                     \
    } while (0)

    // prologue: t=0 data + group w*4 expanded + group w*4+1 raw in flight
    QLD(qa);
    GRP_LOAD(w * 4);
    GRP_EXPAND();
    GRP_LOAD(w * 4 + 1);
    ALD(afa0, afa1, 0);

#pragma unroll
    for (int tt = 0; tt < 8; ++tt) {
        QLD(qb);                        // rows for t0+1
        ALD(afb0, afb1, 2 * tt + 1);    // A frags for t0+1
        if (tt != 0 && (tt & 1) == 0) { // group boundary at t0 = 4,8,12
            GRP_EXPAND();               // expand group loaded 4 t ago
            GRP_LOAD(w * 4 + tt / 2 + 1);
        }
        COMPUTE(qa, afa0, afa1);        // t0
        if (tt < 7) {
            QLD(qa);                    // rows for t0+2
            ALD(afa0, afa1, 2 * tt + 2);
        }
        COMPUTE(qb, afb0, afb1);        // t0+1
    }

    // ---- epilogue: 2 phases (mblk 0, mblk 1), 64 KB LDS reused ----
    // C/D layout per sub: row = h*4 + r (within 16), phys col = 8c + s
    float bv[4];

    // phase 0: mblk 0 (m = 0..15)
#pragma unroll
    for (int s = 0; s < 8; ++s)
#pragma unroll
        for (int r = 0; r < 4; ++r)
            red[w * 2048 + (h * 4 + r) * 128 + 8 * c + s] = acc0[s][r];
    __syncthreads();
#pragma unroll
    for (int i = 0; i < 4; ++i) {
        int e = i * 512 + tid;       // 0..2047
        float sum = 0.f;
#pragma unroll
        for (int ww = 0; ww < 8; ++ww) sum += red[ww * 2048 + e];
        int m = e >> 7;              // 0..15
        int n = n0 + (e & 127);
        bv[i] = bias[n];
        out[(size_t)m * NOUT + n] = sum + bv[i];
    }
    __syncthreads();

    // phase 1: mblk 1 (m = 16..31)
#pragma unroll
    for (int s = 0; s < 8; ++s)
#pragma unroll
        for (int r = 0; r < 4; ++r)
            red[w * 2048 + (h * 4 + r) * 128 + 8 * c + s] = acc1[s][r];
    __syncthreads();
#pragma unroll
    for (int i = 0; i < 4; ++i) {
        int e = i * 512 + tid;
        float sum = 0.f;
#pragma unroll
        for (int ww = 0; ww < 8; ++ww) sum += red[ww * 2048 + e];
        int m = 16 + (e >> 7);       // 16..31
        int n = n0 + (e & 127);
        out[(size_t)m * NOUT + n] = sum + bv[i];
    }
}

extern "C" void kernel_launch(void* const* d_in, const int* in_sizes, int n_in,
                              void* d_out, int out_size, void* d_ws, size_t ws_size,
                              hipStream_t stream) {
    const float* x       = (const float*)d_in[0];
    const int*   qweight = (const int*)d_in[1];
    const float* scales  = (const float*)d_in[2];
    const int*   qzeros  = (const int*)d_in[3];
    const float* bias    = (const float*)d_in[4];

    _Float16* aws = (_Float16*)d_ws;   // 256 KB A-fragment scratch
    float* out = (float*)d_out;

    prep_a_kernel<<<64, 256, 0, stream>>>(x, aws);
    q4gemm_kernel<<<250, 512, 0, stream>>>(qweight, scales, qzeros, bias, aws, out);
}

// Round 9
// 46.797 us; speedup vs baseline: 1.0865x; 1.0865x over previous
//
#include <hip/hip_runtime.h>
#include <hip/hip_bf16.h>

// int4-dequant GEMM, M=32 (last token), K=4096, N=32000 (of 32064 padded).
// qweight [K][16032] int32, ONE BYTE per word (upper 24 bits zero):
//   lo nibble = even col, hi nibble = odd col. w[k][n] = (q - z)*s, g = k/128.
//
// Round 9 = round 8 with the cvt_pkrtz type fixed (__fp16 vec2 -> bit_cast).
// SINGLE fused kernel (prep kernel + graph edge + d_ws eliminated).
// A fragments are loaded straight from x (512 KB last-token slice, L2/L3
// resident) with the SAME 1-k-step-ahead prefetch slot that previously fed
// the aws loads (r3's fused regression was unprefetched loads + nt; both
// fixed/banned since). f32->f16 via v_cvt_pkrtz (packed, 8/t, VALU slack
// proven in r4). Everything else = r7 structure:
//  - BN=128, 250 blocks, dwordx4 qweight loads, 2-deep register dbuf
//  - scales/qzeros raw words prefetched 1 group (4 t) ahead
//  - dequant: tcomb=(w1<<16)|w0, mask-only nibble extract:
//    even cols: (tcomb & 0x000F000F)|0x64006400, vz=1024+z,   vs=s
//    odd  cols: (tcomb & 0x00F000F0)|0x64006400, vz=1024+16z, vs=s/16
//  - k-bijection kappa(h,j)=8h+j shared by A and B (HW k-order cancels)
//  - epilogue reduction in 2 phases (mblk 0/1), 64 KB LDS reused
// Lane c owns phys cols 8c+s (s=0..7); one dwordx4/row covers all 8 subs.
// No nontemporal loads (measured -4us in r5).

typedef _Float16 f16x8 __attribute__((ext_vector_type(8)));
typedef _Float16 f16x2 __attribute__((ext_vector_type(2)));
typedef __fp16 fp16x2 __attribute__((ext_vector_type(2)));   // cvt_pkrtz return type
typedef float f32x4 __attribute__((ext_vector_type(4)));
typedef int i32x4 __attribute__((ext_vector_type(4)));

#define K_DIM 4096
#define NP 16032       // packed words per qweight/qzeros row
#define NSC 32064      // scales row pitch
#define NOUT 32000
#define S_LEN 64
#define QROWB ((size_t)NP * 4)          // bytes per qweight row
#define QSTEP (32u * (uint32_t)NP * 4u) // byte advance per k-step (32 rows)

__global__ __launch_bounds__(512, 2)
void q4gemm_kernel(const float* __restrict__ x,
                   const int* __restrict__ qw,
                   const float* __restrict__ scales,
                   const int* __restrict__ qzeros,
                   const float* __restrict__ bias,
                   float* __restrict__ out) {
    __shared__ float red[8 * 2048];   // 64 KB, reused across 2 epilogue phases

    const int tid = threadIdx.x;
    const int w = tid >> 6;          // wave 0..7 (K-chunk: k in [512w, 512w+512))
    const int l = tid & 63;
    const int h = l >> 4;            // k lane-group 0..3 (rows 8h+j)
    const int c = l & 15;            // lane's column group: phys cols 8c+s
    const int n0 = blockIdx.x * 128; // 128 output cols per block
    const int np0 = n0 >> 1;         // 64 packed words per block

    const char* qwb = (const char*)qw;
    uint32_t qoff = (uint32_t)((w * 512 + 8 * h) * (size_t)NP + np0 + 4 * c) * 4u;

    // x rows feeding this lane's A fragments (last token of m=c and m=16+c)
    const float* xr0 = x + ((size_t)c * S_LEN + (S_LEN - 1)) * K_DIM;
    const float* xr1 = x + ((size_t)(16 + c) * S_LEN + (S_LEN - 1)) * K_DIM;

    f32x4 acc0[8] = {};   // mblk 0, sub s
    f32x4 acc1[8] = {};   // mblk 1
    f16x2 vz[8], vs[8];   // expanded per-group constants
    f32x4 gsc0, gsc1;     // raw next-group scales (8 cols)
    i32x4 gzw;            // raw next-group zeros (4 words)
    i32x4 qa[8], qb[8];
    f32x4 xa0, xa1, xa2, xa3;   // raw x for t0   (m=c: 0,1; m=16+c: 2,3)
    f32x4 xb0, xb1, xb2, xb3;   // raw x for t0+1

#define QLD(buf)                                                              \
    do {                                                                      \
        _Pragma("unroll") for (int j = 0; j < 8; ++j)                         \
            buf[j] = *(const i32x4*)(qwb + qoff + (size_t)j * QROWB);         \
        qoff += QSTEP;                                                        \
    } while (0)

#define XLD(X0, X1, X2, X3, tloc)                                             \
    do {                                                                      \
        int koff_ = (w * 16 + (tloc)) * 32 + 8 * h;                           \
        X0 = *(const f32x4*)(xr0 + koff_);                                    \
        X1 = *(const f32x4*)(xr0 + koff_ + 4);                                \
        X2 = *(const f32x4*)(xr1 + koff_);                                    \
        X3 = *(const f32x4*)(xr1 + koff_ + 4);                                \
    } while (0)

// pack 2 f32 -> one dword of 2 f16 via v_cvt_pkrtz_f16_f32
#define PKRTZ(lo, hi) \
    __builtin_bit_cast(int, __builtin_amdgcn_cvt_pkrtz((lo), (hi)))

// pack 8 f32 (two f32x4) into one f16x8 fragment
#define CVT(A, U0, U1)                                                        \
    do {                                                                      \
        int4 ai_;                                                             \
        ai_.x = PKRTZ(U0[0], U0[1]);                                          \
        ai_.y = PKRTZ(U0[2], U0[3]);                                          \
        ai_.z = PKRTZ(U1[0], U1[1]);                                          \
        ai_.w = PKRTZ(U1[2], U1[3]);                                          \
        A = __builtin_bit_cast(f16x8, ai_);                                   \
    } while (0)

#define GRP_LOAD(g)                                                           \
    do {                                                                      \
        int gg = (g) > 31 ? 31 : (g);                                         \
        gsc0 = *(const f32x4*)(scales + (size_t)gg * NSC + n0 + 8 * c);       \
        gsc1 = *(const f32x4*)(scales + (size_t)gg * NSC + n0 + 8 * c + 4);   \
        gzw = *(const i32x4*)(qzeros + (size_t)gg * NP + np0 + 4 * c);        \
    } while (0)

#define GRP_EXPAND()                                                          \
    do {                                                                      \
        _Pragma("unroll") for (int s = 0; s < 8; ++s) {                       \
            const int q = s >> 1, o = s & 1;                                  \
            int zn = (gzw[q] >> (4 * o)) & 15;                                \
            int z16 = 0x6400 | (o ? (zn << 4) : zn);                          \
            int zp = z16 | (z16 << 16);                                       \
            vz[s] = __builtin_bit_cast(f16x2, zp);                            \
            float sraw = (s < 4) ? gsc0[s] : gsc1[s - 4];                     \
            float sf = sraw * (o ? 0.0625f : 1.0f);                           \
            _Float16 hf = (_Float16)sf;                                       \
            f16x2 sp = {hf, hf};                                              \
            vs[s] = sp;                                                       \
        }                                                                     \
    } while (0)

#define COMPUTE(buf, A0, A1)                                                  \
    do {                                                                      \
        _Pragma("unroll") for (int q = 0; q < 4; ++q) {                       \
            int tc[4];                                                        \
            _Pragma("unroll") for (int p = 0; p < 4; ++p)                     \
                tc[p] = (buf[2 * p + 1][q] << 16) | buf[2 * p][q];            \
            _Pragma("unroll") for (int o = 0; o < 2; ++o) {                   \
                const int s = 2 * q + o;                                      \
                const int msk = o ? 0x00F000F0 : 0x000F000F;                  \
                int4 bi;                                                      \
                _Pragma("unroll") for (int p = 0; p < 4; ++p) {               \
                    int vqi = (tc[p] & msk) | 0x64006400;                     \
                    f16x2 vq = __builtin_bit_cast(f16x2, vqi);                \
                    f16x2 r = (vq - vz[s]) * vs[s];                           \
                    bi[p] = __builtin_bit_cast(int, r);                       \
                }                                                             \
                f16x8 b = __builtin_bit_cast(f16x8, bi);                      \
                acc0[s] = __builtin_amdgcn_mfma_f32_16x16x32_f16(A0, b, acc0[s], 0, 0, 0); \
                acc1[s] = __builtin_amdgcn_mfma_f32_16x16x32_f16(A1, b, acc1[s], 0, 0, 0); \
            }                                                                 \
        }                                                                     \
    } while (0)

    // prologue: t=0 qweight + x in flight; group w*4 expanded, w*4+1 raw
    QLD(qa);
    XLD(xa0, xa1, xa2, xa3, 0);
    GRP_LOAD(w * 4);
    GRP_EXPAND();
    GRP_LOAD(w * 4 + 1);

#pragma unroll
    for (int tt = 0; tt < 8; ++tt) {
        QLD(qb);                             // qweight rows for t0+1
        XLD(xb0, xb1, xb2, xb3, 2 * tt + 1); // x for t0+1
        if (tt != 0 && (tt & 1) == 0) {      // group boundary at t0 = 4,8,12
            GRP_EXPAND();                    // expand group loaded 4 t ago
            GRP_LOAD(w * 4 + tt / 2 + 1);
        }
        {
            f16x8 a0, a1;
            CVT(a0, xa0, xa1);
            CVT(a1, xa2, xa3);
            COMPUTE(qa, a0, a1);             // t0
        }
        if (tt < 7) {
            QLD(qa);                         // qweight rows for t0+2
            XLD(xa0, xa1, xa2, xa3, 2 * tt + 2);
        }
        {
            f16x8 a0, a1;
            CVT(a0, xb0, xb1);
            CVT(a1, xb2, xb3);
            COMPUTE(qb, a0, a1);             // t0+1
        }
    }

    // ---- epilogue: 2 phases (mblk 0, mblk 1), 64 KB LDS reused ----
    // C/D layout per sub: row = h*4 + r (within 16), phys col = 8c + s
    float bv[4];

    // phase 0: mblk 0 (m = 0..15)
#pragma unroll
    for (int s = 0; s < 8; ++s)
#pragma unroll
        for (int r = 0; r < 4; ++r)
            red[w * 2048 + (h * 4 + r) * 128 + 8 * c + s] = acc0[s][r];
    __syncthreads();
#pragma unroll
    for (int i = 0; i < 4; ++i) {
        int e = i * 512 + tid;       // 0..2047
        float sum = 0.f;
#pragma unroll
        for (int ww = 0; ww < 8; ++ww) sum += red[ww * 2048 + e];
        int m = e >> 7;              // 0..15
        int n = n0 + (e & 127);
        bv[i] = bias[n];
        out[(size_t)m * NOUT + n] = sum + bv[i];
    }
    __syncthreads();

    // phase 1: mblk 1 (m = 16..31)
#pragma unroll
    for (int s = 0; s < 8; ++s)
#pragma unroll
        for (int r = 0; r < 4; ++r)
            red[w * 2048 + (h * 4 + r) * 128 + 8 * c + s] = acc1[s][r];
    __syncthreads();
#pragma unroll
    for (int i = 0; i < 4; ++i) {
        int e = i * 512 + tid;
        float sum = 0.f;
#pragma unroll
        for (int ww = 0; ww < 8; ++ww) sum += red[ww * 2048 + e];
        int m = 16 + (e >> 7);       // 16..31
        int n = n0 + (e & 127);
        out[(size_t)m * NOUT + n] = sum + bv[i];
    }
}

extern "C" void kernel_launch(void* const* d_in, const int* in_sizes, int n_in,
                              void* d_out, int out_size, void* d_ws, size_t ws_size,
                              hipStream_t stream) {
    const float* x       = (const float*)d_in[0];
    const int*   qweight = (const int*)d_in[1];
    const float* scales  = (const float*)d_in[2];
    const int*   qzeros  = (const int*)d_in[3];
    const float* bias    = (const float*)d_in[4];
    float* out = (float*)d_out;

    q4gemm_kernel<<<250, 512, 0, stream>>>(x, qweight, scales, qzeros, bias, out);
}